// Round 5
// baseline (4630.487 us; speedup 1.0000x reference)
//
#include <hip/hip_runtime.h>
#include <cstdint>
#include <cstddef>

// LSTM: IC=HC=512, L=2, T=512, BS=64.  out = [T,64,512] fp32, hs/cs = [2,64,512] fp32.
// R5: XCD-LOCAL recurrence. Layer 0 lives on XCD 0 (32 WGs, 1/CU, 128KB weights in
// LDS each), layer 1 on XCD 1.  h exchange via normal per-XCD-L2 stores/loads
// (fresh address per t; sc0 polls bypass L1).  Per-wave flags (vmcnt is per-wave)
// -> no __syncthreads in the loop.  L0->L1 feed via MALL (agent) with 1-step lag.
// WGs claim slots by XCC_ID at runtime -> correct under any dispatch/XCD mapping.

#define T_STEPS 512
#define WROW 1032   // LDS row stride (bf16): 1024 + 8 pad

typedef float f32x4 __attribute__((ext_vector_type(4)));
typedef short s16x8 __attribute__((ext_vector_type(8)));

__device__ __forceinline__ unsigned short f2bf(float f) {
    unsigned int u = __builtin_bit_cast(unsigned int, f);
    u += 0x7FFFu + ((u >> 16) & 1u);          // round-to-nearest-even
    return (unsigned short)(u >> 16);
}
__device__ __forceinline__ float sig_(float x)  { return 1.0f / (1.0f + __expf(-x)); }
__device__ __forceinline__ float tanh_(float x) { return 1.0f - 2.0f / (__expf(2.0f * x) + 1.0f); }

// L1-bypassing, L2-hitting load (intra-XCD flag poll of a repeatedly-read address).
__device__ __forceinline__ unsigned int ld_sc0(const unsigned int* p) {
    unsigned int v;
    asm volatile("global_load_dword %0, %1, off sc0\n\ts_waitcnt vmcnt(0)"
                 : "=v"(v) : "v"(p) : "memory");
    return v;
}
__device__ __forceinline__ void st_sc0(unsigned int* p, unsigned int v) {
    asm volatile("global_store_dword %0, %1, off sc0" :: "v"(p), "v"(v) : "memory");
}
// MALL (agent) flag store / data store
__device__ __forceinline__ void st_sc01(unsigned int* p, unsigned int v) {
    asm volatile("global_store_dword %0, %1, off sc0 sc1" :: "v"(p), "v"(v) : "memory");
}
__device__ __forceinline__ void st_b128_sc01(unsigned short* p, s16x8 v) {
    asm volatile("global_store_dwordx4 %0, %1, off sc0 sc1" :: "v"(p), "v"(v) : "memory");
}
#define WAIT_VM0() asm volatile("s_waitcnt vmcnt(0)" ::: "memory")

// ---- prep kernels -------------------------------------------------------

__global__ void k_conv_bf16(const float* __restrict__ src, unsigned short* __restrict__ dst) {
    int i = (blockIdx.x * 256 + threadIdx.x) * 8;
    float4 a = *(const float4*)(src + i);
    float4 b = *(const float4*)(src + i + 4);
    s16x8 o;
    o[0]=(short)f2bf(a.x); o[1]=(short)f2bf(a.y); o[2]=(short)f2bf(a.z); o[3]=(short)f2bf(a.w);
    o[4]=(short)f2bf(b.x); o[5]=(short)f2bf(b.y); o[6]=(short)f2bf(b.z); o[7]=(short)f2bf(b.w);
    *(s16x8*)(dst + i) = o;
}

__global__ void k_transpose_w(const float* __restrict__ W0, const float* __restrict__ W1,
                              unsigned short* __restrict__ WT0, unsigned short* __restrict__ WT1) {
    __shared__ unsigned short tile[32][33];
    const float* W = blockIdx.z ? W1 : W0;
    unsigned short* WT = blockIdx.z ? WT1 : WT0;
    int n0 = blockIdx.x * 32, k0 = blockIdx.y * 32;
    int tx = threadIdx.x, ty = threadIdx.y;       // (32,8)
    #pragma unroll
    for (int i = 0; i < 4; i++)
        tile[ty + i*8][tx] = f2bf(W[(size_t)(k0 + ty + i*8) * 2048 + n0 + tx]);
    __syncthreads();
    #pragma unroll
    for (int i = 0; i < 4; i++)
        WT[(size_t)(n0 + ty + i*8) * 1024 + k0 + tx] = tile[tx][ty + i*8];
}

// h0 [2][1][512] -> packed [wg(32)][b(64)][16] bf16 per layer.
__global__ void k_hinit(const float* __restrict__ h0, unsigned short* __restrict__ hi0,
                        unsigned short* __restrict__ hi1) {
    int idx = blockIdx.x * 256 + threadIdx.x;   // 65536 total
    int layer = idx >> 15;
    int r = idx & 32767;
    int b = r >> 9;
    int j = r & 511;
    unsigned short v = f2bf(h0[layer * 512 + j]);
    unsigned short* d = layer ? hi1 : hi0;
    d[(size_t)((j >> 4) * 64 + b) * 16 + (j & 15)] = v;
}

// ---- XCD-local persistent recurrence kernel -----------------------------
// Worker WG (rank wg on its layer's XCD) owns hidden cols j0=16wg..16wg+15 (all 4 gates).
// LDS Wl[64][WROW]: rows g*16+c hold W[k][g*512+j0+c].
// h packed [t][wg(32)][b(64)][16] bf16.  Intra flags fl[layer][t][128] (u32, 4B stride,
// value t+1); x-feed flags xfl[t][128] agent-scope, written with 1-step lag.
__global__ __launch_bounds__(256, 1) void k_lstm(
    const unsigned short* __restrict__ xb,
    const unsigned short* __restrict__ hi0, const unsigned short* __restrict__ hi1,
    const unsigned short* __restrict__ WT0, const unsigned short* __restrict__ WT1,
    const float* __restrict__ b0, const float* __restrict__ b1,
    const float* __restrict__ c0,
    unsigned short* __restrict__ h0s, unsigned short* __restrict__ h1s,
    unsigned short* __restrict__ h0x,
    float* __restrict__ out, float* __restrict__ hs, float* __restrict__ cs,
    unsigned int* __restrict__ fl, unsigned int* __restrict__ xfl,
    unsigned int* __restrict__ claim)
{
    __shared__ unsigned short Wl[64][WROW];     // 132,096 B
    __shared__ unsigned short hstage[64][16];   //   2,048 B
    __shared__ int sLayer, sRank;

    const int tid = threadIdx.x;
    if (tid == 0) {
        // HW_REG 20 (XCC_ID), offset 0, size 4  -> imm = 20 | (3<<11) = 6164
        unsigned int xcd = __builtin_amdgcn_s_getreg(6164);
        int layer = -1, rank = 0;
        if (xcd <= 1u) {
            rank = (int)__hip_atomic_fetch_add(claim + xcd, 1u,
                                               __ATOMIC_RELAXED, __HIP_MEMORY_SCOPE_AGENT);
            if (rank < 32) layer = (int)xcd;
        }
        sLayer = layer; sRank = rank;
    }
    __syncthreads();
    const int layer = sLayer;
    const int wg = sRank;
    if (layer < 0) return;

    const unsigned short* WT    = layer ? WT1 : WT0;
    const float*          bias  = layer ? b1  : b0;
    const float*          c0l   = c0 + layer * 512;
    const unsigned short* hinit = layer ? hi1 : hi0;
    unsigned short*       hseq  = layer ? h1s : h0s;
    unsigned int*         fl_own = fl + (size_t)layer * T_STEPS * 128;
    const int j0 = wg * 16;

    // Load weight slice: 64 rows x 1024 bf16 = 128 KB, coalesced b128 chunks.
    #pragma unroll
    for (int it = 0; it < 32; it++) {
        int idx = it * 256 + tid;          // 0..8191 = 64 rows * 128 chunks
        int row = idx >> 7;
        int ch  = idx & 127;
        int gate = row >> 4;
        int cl   = row & 15;
        int gcol = gate * 512 + j0 + cl;
        *(s16x8*)(&Wl[row][ch * 8]) = *(const s16x8*)(WT + (size_t)gcol * 1024 + ch * 8);
    }
    __syncthreads();

    const int lane = tid & 63;
    const int wv = tid >> 6;          // wave: batch rows [16wv,16wv+16)
    const int q = lane >> 4;
    const int cc = lane & 15;         // MFMA col = hidden col j0+cc
    const int arow = wv * 16 + cc;    // A-frag batch row
    const int jj = j0 + cc;
    const int bb = wv * 16 + q * 4;   // C/D batch row base

    const float bF = bias[jj], bI = bias[512 + jj], bO = bias[1024 + jj], bG = bias[1536 + jj];
    float cst[4];
    { float ci = c0l[jj]; cst[0]=cst[1]=cst[2]=cst[3]=ci; }

    const int fidx = wg * 4 + wv;     // this wave's flag slot (0..127)

    for (int t = 0; t < T_STEPS; t++) {
        f32x4 aF = {bF,bF,bF,bF}, aI = {bI,bI,bI,bI};
        f32x4 aO = {bO,bO,bO,bO}, aG = {bG,bG,bG,bG};

        // ---------- x-half ----------
        if (layer == 0) {
            const unsigned short* xp = xb + (size_t)(t * 64 + arow) * 512 + q * 8;
            #pragma unroll
            for (int kk = 0; kk < 16; kk++) {
                s16x8 a = *(const s16x8*)(xp + kk * 32);
                s16x8 wF = *(const s16x8*)(&Wl[cc     ][kk * 32 + q * 8]);
                s16x8 wI = *(const s16x8*)(&Wl[16 + cc][kk * 32 + q * 8]);
                s16x8 wO = *(const s16x8*)(&Wl[32 + cc][kk * 32 + q * 8]);
                s16x8 wG = *(const s16x8*)(&Wl[48 + cc][kk * 32 + q * 8]);
                aF = __builtin_amdgcn_mfma_f32_16x16x32_bf16(a, wF, aF, 0, 0, 0);
                aI = __builtin_amdgcn_mfma_f32_16x16x32_bf16(a, wI, aI, 0, 0, 0);
                aO = __builtin_amdgcn_mfma_f32_16x16x32_bf16(a, wO, aO, 0, 0, 0);
                aG = __builtin_amdgcn_mfma_f32_16x16x32_bf16(a, wG, aG, 0, 0, 0);
            }
        } else {
            // wait for L0's MALL feed of step t (agent polls bypass L2 -> no stale line)
            {
                const unsigned int* p = xfl + (size_t)t * 128 + lane;
                while (__hip_atomic_load(p, __ATOMIC_RELAXED, __HIP_MEMORY_SCOPE_AGENT)
                       != (unsigned int)(t + 1))
                    __builtin_amdgcn_s_sleep(2);
                p += 64;
                while (__hip_atomic_load(p, __ATOMIC_RELAXED, __HIP_MEMORY_SCOPE_AGENT)
                       != (unsigned int)(t + 1))
                    __builtin_amdgcn_s_sleep(2);
            }
            const unsigned short* xp = h0x + (size_t)t * 32768;
            #pragma unroll
            for (int kk = 0; kk < 16; kk++) {
                s16x8 a = *(const s16x8*)(xp + (size_t)(2*kk + (q>>1)) * 1024 + arow * 16 + (q&1) * 8);
                s16x8 wF = *(const s16x8*)(&Wl[cc     ][kk * 32 + q * 8]);
                s16x8 wI = *(const s16x8*)(&Wl[16 + cc][kk * 32 + q * 8]);
                s16x8 wO = *(const s16x8*)(&Wl[32 + cc][kk * 32 + q * 8]);
                s16x8 wG = *(const s16x8*)(&Wl[48 + cc][kk * 32 + q * 8]);
                aF = __builtin_amdgcn_mfma_f32_16x16x32_bf16(a, wF, aF, 0, 0, 0);
                aI = __builtin_amdgcn_mfma_f32_16x16x32_bf16(a, wI, aI, 0, 0, 0);
                aO = __builtin_amdgcn_mfma_f32_16x16x32_bf16(a, wO, aO, 0, 0, 0);
                aG = __builtin_amdgcn_mfma_f32_16x16x32_bf16(a, wG, aG, 0, 0, 0);
            }
        }

        // ---------- wait own peers (step t-1), intra-XCD ----------
        if (t > 0) {
            const unsigned int* p = fl_own + (size_t)(t - 1) * 128 + lane;
            while (ld_sc0(p) != (unsigned int)t) __builtin_amdgcn_s_sleep(1);
            p += 64;
            while (ld_sc0(p) != (unsigned int)t) __builtin_amdgcn_s_sleep(1);
        }

        // ---------- h-half (normal L2 loads, fresh addresses) ----------
        {
            const unsigned short* hb = t ? (hseq + (size_t)(t - 1) * 32768) : hinit;
            #pragma unroll
            for (int kk = 0; kk < 16; kk++) {
                s16x8 a = *(const s16x8*)(hb + (size_t)(2*kk + (q>>1)) * 1024 + arow * 16 + (q&1) * 8);
                s16x8 wF = *(const s16x8*)(&Wl[cc     ][512 + kk * 32 + q * 8]);
                s16x8 wI = *(const s16x8*)(&Wl[16 + cc][512 + kk * 32 + q * 8]);
                s16x8 wO = *(const s16x8*)(&Wl[32 + cc][512 + kk * 32 + q * 8]);
                s16x8 wG = *(const s16x8*)(&Wl[48 + cc][512 + kk * 32 + q * 8]);
                aF = __builtin_amdgcn_mfma_f32_16x16x32_bf16(a, wF, aF, 0, 0, 0);
                aI = __builtin_amdgcn_mfma_f32_16x16x32_bf16(a, wI, aI, 0, 0, 0);
                aO = __builtin_amdgcn_mfma_f32_16x16x32_bf16(a, wO, aO, 0, 0, 0);
                aG = __builtin_amdgcn_mfma_f32_16x16x32_bf16(a, wG, aG, 0, 0, 0);
            }
        }

        // ---------- gates (fp32, all in-lane) ----------
        float hv4[4];
        #pragma unroll
        for (int r = 0; r < 4; r++) {
            float fg = sig_(aF[r] + 1.0f);     // FORGET_BIAS
            float ig = sig_(aI[r]);
            float og = sig_(aO[r]);
            float gg = tanh_(aG[r]);
            float cn = cst[r] * fg + gg * ig;
            cst[r] = cn;
            float hv = og * tanh_(cn);
            hv4[r] = hv;
            hstage[bb + r][cc] = f2bf(hv);     // wave-local rows
        }

        // ---------- per-wave publish: intra stores -> vmcnt drain -> flags ----------
        unsigned short* dst = hseq + (size_t)t * 32768 + wg * 1024;
        if (lane < 32) {
            int row = wv * 16 + (lane >> 1);
            int half = lane & 1;
            s16x8 v = *(const s16x8*)(&hstage[row][half * 8]);
            *(s16x8*)(dst + row * 16 + half * 8) = v;
        }
        WAIT_VM0();   // drains: this step's intra h stores + last step's MALL stores
        if (lane == 0) {
            st_sc0(fl_own + (size_t)t * 128 + fidx, (unsigned int)(t + 1));
            if (layer == 0 && t > 0)
                st_sc01(xfl + (size_t)(t - 1) * 128 + fidx, (unsigned int)t);
        }
        // MALL copy of this step's h (L0 only), flagged next step (lag-1)
        if (layer == 0 && lane < 32) {
            int row = wv * 16 + (lane >> 1);
            int half = lane & 1;
            s16x8 v = *(const s16x8*)(&hstage[row][half * 8]);
            st_b128_sc01(h0x + (size_t)t * 32768 + wg * 1024 + row * 16 + half * 8, v);
        }

        // ---------- off-critical-path outputs ----------
        if (layer == 1) {
            #pragma unroll
            for (int r = 0; r < 4; r++)
                out[(size_t)(t * 64 + bb + r) * 512 + jj] = hv4[r];
        }
        if (t == T_STEPS - 1) {
            #pragma unroll
            for (int r = 0; r < 4; r++) {
                hs[(size_t)(layer * 64 + bb + r) * 512 + jj] = hv4[r];
                cs[(size_t)(layer * 64 + bb + r) * 512 + jj] = cst[r];
            }
        }
    }

    // final x-feed flag for t=511
    if (layer == 0) {
        WAIT_VM0();
        if (lane == 0)
            st_sc01(xfl + (size_t)(T_STEPS - 1) * 128 + fidx, (unsigned int)T_STEPS);
    }
}

// ---- launch -------------------------------------------------------------

extern "C" void kernel_launch(void* const* d_in, const int* in_sizes, int n_in,
                              void* d_out, int out_size, void* d_ws, size_t ws_size,
                              hipStream_t stream) {
    const float* x  = (const float*)d_in[0];
    const float* W0 = (const float*)d_in[1];
    const float* b0 = (const float*)d_in[2];
    const float* W1 = (const float*)d_in[3];
    const float* b1 = (const float*)d_in[4];
    const float* h0 = (const float*)d_in[5];
    const float* c0 = (const float*)d_in[6];
    float* out = (float*)d_out;

    char* ws = (char*)d_ws;
    unsigned short* xb  = (unsigned short*)(ws);                    // 33,554,432 B
    unsigned short* h0s = (unsigned short*)(ws + 33554432ul);       // 33,554,432 B (XCD0 L2)
    unsigned short* h1s = (unsigned short*)(ws + 67108864ul);       // 33,554,432 B (XCD1 L2)
    unsigned short* h0x = (unsigned short*)(ws + 100663296ul);      // 33,554,432 B (MALL feed)
    unsigned short* WT0 = (unsigned short*)(ws + 134217728ul);      //  4,194,304 B
    unsigned short* WT1 = (unsigned short*)(ws + 138412032ul);      //  4,194,304 B
    unsigned short* hi0 = (unsigned short*)(ws + 142606336ul);      //     65,536 B
    unsigned short* hi1 = (unsigned short*)(ws + 142671872ul);      //     65,536 B
    unsigned int*   fl  = (unsigned int*)  (ws + 142737408ul);      //    524,288 B
    unsigned int*   xfl = (unsigned int*)  (ws + 143261696ul);      //    262,144 B
    unsigned int*   claim = (unsigned int*)(ws + 143523840ul);      //        256 B

    hipMemsetAsync(claim, 0, 256, stream);
    k_conv_bf16<<<8192, 256, 0, stream>>>(x, xb);
    k_transpose_w<<<dim3(64, 32, 2), dim3(32, 8), 0, stream>>>(W0, W1, WT0, WT1);
    k_hinit<<<256, 256, 0, stream>>>(h0, hi0, hi1);

    float* hs = out + 16777216;            // [2][64][512]
    float* cs = hs + 65536;                // [2][64][512]
    k_lstm<<<512, 256, 0, stream>>>(xb, hi0, hi1, WT0, WT1, b0, b1, c0,
                                    h0s, h1s, h0x, out, hs, cs, fl, xfl, claim);
}